// Round 10
// baseline (596.642 us; speedup 1.0000x reference)
//
#include <hip/hip_runtime.h>
#include <cstddef>
#include <cstdint>

#define S_TOK 8192
#define DDIM  2048
#define NEXP  64
#define CAPTY 128
#define KC    64
#define TPB   64                       // tokens per chunk
#define NBLK  (S_TOK / TPB)            // 128 chunks
#define SPLITK 8
#define KPER  (DDIM / SPLITK)          // 256
#define SEC   ((size_t)S_TOK * NEXP * CAPTY)   // 67,108,864
#define NOUT  ((size_t)1 + 2 * SEC)            // 134,217,729 floats

// ---------------------------------------------------------------------------
// SESSION LEDGER (rounds 0-9, best = R2/R9 @ ~594us):
//  - 2 GiB fillBufferAligned (~345us) = HARNESS poison of the full output
//    allocation, inside the timed window, untouchable.
//  - out_size is an ELEMENT count; our memset = 512 MiB logical region,
//    mandatory (output mostly zeros, re-poisoned every iteration), ~85us at
//    the measured 6.3 TB/s fill ceiling. rocclr fill path is optimal:
//    R4 (fill-only blocks) +22us, R7 (NT stores in GEMM loop) +12us.
//  - GEMM restructures flat/worse: R5 8x8/64thr +7, R6 4x8/128thr +9,
//    R8 scalar-W +76. R2's 4x4/256thr staging GEMM is the measured optimum.
//  - R10 (this file): scan_kernel folded into scatter (5 -> 4 dispatches);
//    all arithmetic orders preserved -> bit-identical output.
// ---------------------------------------------------------------------------

// ---------------------------------------------------------------------------
// Kernel 1: split-K fp32 GEMM, coalesced staging (R2, measured best).
// ---------------------------------------------------------------------------
__global__ __launch_bounds__(256)
void gate_gemm_kernel(const float* __restrict__ x, const float* __restrict__ wg,
                      float* __restrict__ part)
{
    __shared__ float xs[TPB][72];       // 18,432 B
    __shared__ float ws[KC][NEXP];      // 16,384 B  (34.8 KB total -> 4 blk/CU)

    const int tid = threadIdx.x;
    const int el  = tid & 15;           // experts 4*el..4*el+3
    const int tg  = tid >> 4;           // tokens  tg, tg+16, tg+32, tg+48
    const int kp  = blockIdx.x & (SPLITK - 1);
    const int tc  = blockIdx.x >> 3;
    const int t_base = tc * TPB;
    const int k_base = kp * KPER;

    float acc[4][4];                    // [token i][expert j]
#pragma unroll
    for (int i = 0; i < 4; ++i)
#pragma unroll
        for (int j = 0; j < 4; ++j) acc[i][j] = 0.0f;

    for (int kc0 = 0; kc0 < KPER; kc0 += KC) {
        const int kc = k_base + kc0;
        __syncthreads();
        // stage x: 16 consecutive lanes read 256 contiguous bytes of one row
#pragma unroll
        for (int m = 0; m < 4; ++m) {
            int idx = tid + 256 * m;        // 0..1023
            int t = idx >> 4;               // row 0..63
            int c = idx & 15;               // float4 col 0..15
            float4 v = *(const float4*)(x + (size_t)(t_base + t) * DDIM + kc + c * 4);
            *(float4*)&xs[t][c * 4] = v;    // aligned b128, ~2-way banks
        }
        // stage wg: scatter along k (L2-absorbed), conflict-free b32 LDS writes
#pragma unroll
        for (int m = 0; m < 4; ++m) {
            int idx = tid + 256 * m;
            int e = idx & 63;               // expert row
            int c = idx >> 6;               // float4 col 0..15
            float4 w = *(const float4*)(wg + (size_t)e * DDIM + kc + c * 4);
            ws[c * 4 + 0][e] = w.x;
            ws[c * 4 + 1][e] = w.y;
            ws[c * 4 + 2][e] = w.z;
            ws[c * 4 + 3][e] = w.w;
        }
        __syncthreads();

#pragma unroll
        for (int k4 = 0; k4 < KC; k4 += 4) {
            float4 xv[4], wv[4];
#pragma unroll
            for (int i = 0; i < 4; ++i)
                xv[i] = *(const float4*)&xs[tg + 16 * i][k4];   // banks disjoint
#pragma unroll
            for (int j = 0; j < 4; ++j)
                wv[j] = *(const float4*)&ws[k4 + j][el * 4];    // 2-way banks
#pragma unroll
            for (int i = 0; i < 4; ++i) {
                acc[i][0] += xv[i].x * wv[0].x; acc[i][1] += xv[i].x * wv[0].y;
                acc[i][2] += xv[i].x * wv[0].z; acc[i][3] += xv[i].x * wv[0].w;
                acc[i][0] += xv[i].y * wv[1].x; acc[i][1] += xv[i].y * wv[1].y;
                acc[i][2] += xv[i].y * wv[1].z; acc[i][3] += xv[i].y * wv[1].w;
                acc[i][0] += xv[i].z * wv[2].x; acc[i][1] += xv[i].z * wv[2].y;
                acc[i][2] += xv[i].z * wv[2].z; acc[i][3] += xv[i].z * wv[2].w;
                acc[i][0] += xv[i].w * wv[3].x; acc[i][1] += xv[i].w * wv[3].y;
                acc[i][2] += xv[i].w * wv[3].z; acc[i][3] += xv[i].w * wv[3].w;
            }
        }
    }

#pragma unroll
    for (int i = 0; i < 4; ++i) {
        int t = tg + 16 * i;
        float4 v = make_float4(acc[i][0], acc[i][1], acc[i][2], acc[i][3]);
        *(float4*)(part + ((size_t)kp * S_TOK + t_base + t) * NEXP + el * 4) = v;
    }
}

// ---------------------------------------------------------------------------
// Kernel 2: reduce split-K partials + softmax/argmax/rank/hist per chunk.
// 128 blocks x 256 threads (4 threads per token for the reduction).
// ---------------------------------------------------------------------------
__global__ __launch_bounds__(256)
void softmax_kernel(const float* __restrict__ part,
                    float* __restrict__ gate_s, int* __restrict__ expert,
                    int* __restrict__ rank, int* __restrict__ hist,
                    float* __restrict__ partial_g)
{
    __shared__ float probs[TPB][NEXP + 1];
    __shared__ int   sexp[TPB];

    const int tid = threadIdx.x;
    const int t_base = blockIdx.x * TPB;
    const int t = tid >> 2, q = tid & 3;    // 4 threads per token
    const int tok = t_base + t;

#pragma unroll
    for (int jj = 0; jj < 4; ++jj) {
        float4 a = make_float4(0.f, 0.f, 0.f, 0.f);
#pragma unroll
        for (int kpp = 0; kpp < SPLITK; ++kpp) {
            float4 v = *(const float4*)(part + ((size_t)kpp * S_TOK + tok) * NEXP + q * 16 + jj * 4);
            a.x += v.x; a.y += v.y; a.z += v.z; a.w += v.w;
        }
        probs[t][q * 16 + jj * 4 + 0] = a.x;
        probs[t][q * 16 + jj * 4 + 1] = a.y;
        probs[t][q * 16 + jj * 4 + 2] = a.z;
        probs[t][q * 16 + jj * 4 + 3] = a.w;
    }
    __syncthreads();

    if (tid < TPB) {                    // one thread per token
        const int t2 = tid, tok2 = t_base + t2;
        float m = -1e30f; int am = 0;
        for (int e = 0; e < NEXP; ++e) {
            float v = probs[t2][e];
            if (v > m) { m = v; am = e; }       // strict > = np.argmax
        }
        float s = 0.0f;
        for (int e = 0; e < NEXP; ++e) s += __expf(probs[t2][e] - m);
        float rcp = 1.0f / s;                   // top-1 gate value
        for (int e = 0; e < NEXP; ++e)
            probs[t2][e] = __expf(probs[t2][e] - m) * rcp;
        sexp[t2] = am;
        gate_s[tok2] = rcp;
        expert[tok2] = am;
    }
    __syncthreads();

    if (tid < TPB) {                    // rank within chunk (token order)
        const int t2 = tid;
        const int am = sexp[t2];
        int r = 0;
        for (int u = 0; u < t2; ++u) r += (sexp[u] == am) ? 1 : 0;
        rank[t_base + t2] = r;
    } else if (tid < 2 * TPB) {         // per-expert histogram + gate sums
        const int e = tid - TPB;
        float pg = 0.0f; int cnt = 0;
        for (int u = 0; u < TPB; ++u) {
            pg  += probs[u][e];
            cnt += (sexp[u] == e) ? 1 : 0;
        }
        partial_g[blockIdx.x * NEXP + e] = pg;
        hist[blockIdx.x * NEXP + e]      = cnt;
    }
}

// ---------------------------------------------------------------------------
// Kernel 3 (fused scan+scatter): 32 blocks x 256 threads.
//  Phase A, wave 0 (tid<64 = expert e): exclusive per-expert prefix over
//  chunks [0, 4b) (8-wide batched, hist is L2-hot 32KB), then the 4 bases
//  for this block's chunks -> LDS. Block 0's wave 1 (tid 64..127 = expert e)
//  computes l_aux with R9's exact summation order (c ascending, batched 8,
//  then shfl_down butterfly) -> out[0]. Phase B: all 256 threads scatter
//  their token. Saves one dispatch (the 1-block scan) per iteration.
// ---------------------------------------------------------------------------
__global__ __launch_bounds__(256)
void scatter_scan_kernel(const float* __restrict__ gate_s, const int* __restrict__ expert,
                         const int* __restrict__ rank, const int* __restrict__ hist,
                         const float* __restrict__ partial_g, float* __restrict__ out)
{
    __shared__ int sbase[4][NEXP];
    const int b   = blockIdx.x;        // 0..31
    const int tid = threadIdx.x;
    const int c0  = b * 4;             // first chunk handled by this block

    if (tid < NEXP) {
        const int e = tid;
        int base = 0;
        int c = 0;
        for (; c + 8 <= c0; c += 8) {          // batched prefix (L2-hot)
            int h[8];
#pragma unroll
            for (int j = 0; j < 8; ++j) h[j] = hist[(c + j) * NEXP + e];
#pragma unroll
            for (int j = 0; j < 8; ++j) base += h[j];
        }
        for (; c < c0; ++c) base += hist[c * NEXP + e];
#pragma unroll
        for (int j = 0; j < 4; ++j) {          // bases for own 4 chunks
            sbase[j][e] = base;
            base += hist[(c0 + j) * NEXP + e];
        }
    } else if (b == 0 && tid < 2 * NEXP) {
        const int e = tid - NEXP;              // wave 1, lane e
        int   cnt = 0;
        float sg  = 0.0f;
        for (int c = 0; c < NBLK; c += 8) {
            int h[8]; float g[8];
#pragma unroll
            for (int j = 0; j < 8; ++j) {
                h[j] = hist[(c + j) * NEXP + e];
                g[j] = partial_g[(c + j) * NEXP + e];
            }
#pragma unroll
            for (int j = 0; j < 8; ++j) { cnt += h[j]; sg += g[j]; }
        }
        float v = sg * (float)cnt;             // sum_gates[e] * pre-drop count[e]
#pragma unroll
        for (int off = 32; off > 0; off >>= 1) v += __shfl_down(v, off);
        if (e == 0)
            out[0] = v * (64.0f / (8192.0f * 8192.0f));   // l_aux
    }
    __syncthreads();

    const int s = b * 256 + tid;
    const int e = expert[s];
    const int loc = sbase[(s >> 6) - c0][e] + rank[s];
    if (loc < CAPTY) {
        size_t idx = 1 + (size_t)s * (NEXP * CAPTY) + (size_t)e * CAPTY + loc;
        out[idx]       = gate_s[s];     // combine1_sec
        out[idx + SEC] = 1.0f;          // dispatch_mask
    }
}

extern "C" void kernel_launch(void* const* d_in, const int* in_sizes, int n_in,
                              void* d_out, int out_size, void* d_ws, size_t ws_size,
                              hipStream_t stream)
{
    const float* x  = (const float*)d_in[0];
    const float* wg = (const float*)d_in[1];
    float* out = (float*)d_out;
    char* ws = (char*)d_ws;

    float* part      = (float*)(ws + 0);                       // 16 MB
    size_t off = (size_t)SPLITK * S_TOK * NEXP * sizeof(float);
    float* gate_s    = (float*)(ws + off);          off += 32768;
    int*   expert    = (int*)  (ws + off);          off += 32768;
    int*   rank      = (int*)  (ws + off);          off += 32768;
    int*   hist      = (int*)  (ws + off);          off += 32768;
    float* partial_g = (float*)(ws + off);          off += 32768;

    gate_gemm_kernel<<<NBLK * SPLITK, 256, 0, stream>>>(x, wg, part);
    softmax_kernel<<<NBLK, 256, 0, stream>>>(part, gate_s, expert, rank, hist, partial_g);
    hipMemsetAsync(d_out, 0, NOUT * sizeof(float), stream);
    scatter_scan_kernel<<<S_TOK / 256, 256, 0, stream>>>(gate_s, expert, rank,
                                                         hist, partial_g, out);
}